// Round 1
// baseline (913.350 us; speedup 1.0000x reference)
//
#include <hip/hip_runtime.h>
#include <hip/hip_bf16.h>
#include <math.h>

#define NPTS   65536
#define NS     16
#define WID    128
#define NHID   3
#define CAP    24576        // per-subdomain bucket capacity (expected ~20.5k)
#define CUTOFF 1e-12f       // skip (point,s) pairs with wm below this; err <= ~1e-10 << 1.3e-9
#define PADH   68           // padded row stride (floats) for h tiles in LDS

// ws layout (needs ~4.72 MB):
//   [0,64)            : counts[16]
//   [256, 256+16*CAP*4): idx buckets
//   [1573120, +3145728): WhT (16 x 3 x 128 x 128 transposed hidden weights)
#define OFF_IDX 256
#define OFF_WHT 1573120

__device__ __forceinline__ float sigmf(float z) { return 1.f / (1.f + expf(-z)); }

__global__ void zero_kernel(float* out, int* counts) {
    int i = blockIdx.x * 256 + threadIdx.x;
    if (i < NPTS) out[i] = 0.f;
    if (i < NS) counts[i] = 0;
}

// WhT[sl][w][v] = Wh[sl][v][w]   (sl = s*3+l), output-coalesced float4 writes
__global__ void transpose_kernel(const float* __restrict__ Wh, float* __restrict__ WhT) {
    int o4 = blockIdx.x * 256 + threadIdx.x;   // 196608 float4s total
    int o  = o4 * 4;
    int sl = o >> 14;          // / (128*128)
    int rem = o & 16383;
    int w = rem >> 7;
    int v = rem & 127;         // multiple of 4
    const float* src = Wh + (sl << 14);
    float4 val;
    val.x = src[(v + 0) * WID + w];
    val.y = src[(v + 1) * WID + w];
    val.z = src[(v + 2) * WID + w];
    val.w = src[(v + 3) * WID + w];
    ((float4*)WhT)[o4] = val;
}

__global__ void bucket_kernel(const float* __restrict__ x,
                              const float* __restrict__ mu_min, const float* __restrict__ sd_min,
                              const float* __restrict__ mu_max, const float* __restrict__ sd_max,
                              int* counts, int* __restrict__ idx) {
    __shared__ int lcnt[NS];
    __shared__ int lbase[NS];
    __shared__ unsigned short litem[NS][256];
    int t = threadIdx.x;
    if (t < NS) lcnt[t] = 0;
    __syncthreads();
    int n = blockIdx.x * 256 + t;
    float xv = x[n];
    for (int s = 0; s < NS; ++s) {
        float wl = sigmf((xv - mu_min[s]) / sd_min[s]);
        float wh = sigmf((mu_max[s] - xv) / sd_max[s]);
        if (wl * wh > CUTOFF) {
            int pos = atomicAdd(&lcnt[s], 1);
            litem[s][pos] = (unsigned short)t;
        }
    }
    __syncthreads();
    if (t < NS) lbase[t] = atomicAdd(&counts[t], lcnt[t]);
    __syncthreads();
    int blockbase = blockIdx.x * 256;
    for (int s = 0; s < NS; ++s) {
        int c = lcnt[s], b = lbase[s];
        for (int j = t; j < c; j += 256) {
            int g = b + j;
            if (g < CAP) idx[s * CAP + g] = blockbase + (int)litem[s][j];
        }
    }
}

__global__ __launch_bounds__(256) void mlp_kernel(
        const float* __restrict__ x,
        const float* __restrict__ W0,   const float* __restrict__ b0,
        const float* __restrict__ WhT,  const float* __restrict__ bh,
        const float* __restrict__ Wout, const float* __restrict__ bout,
        const float* __restrict__ centres, const float* __restrict__ scales,
        const float* __restrict__ mu_min,  const float* __restrict__ sd_min,
        const float* __restrict__ mu_max,  const float* __restrict__ sd_max,
        const int* __restrict__ counts, const int* __restrict__ idx,
        float* __restrict__ out) {
    __shared__ float WTs[WID * WID];        // 64 KB: one hidden layer, transposed [w][v]
    __shared__ float hbuf[2][WID * PADH];   // 2 x 34 KB ping-pong, layout [w][p]
    __shared__ float xi_s[64], wm_s[64];
    __shared__ int   nn_s[64];
    __shared__ float red[4][64];

    int s = blockIdx.x;
    int cnt = counts[s]; if (cnt > CAP) cnt = CAP;
    int base = blockIdx.y * 64;
    if (base >= cnt) return;               // uniform early-out, before any barrier
    int t = threadIdx.x;

    if (t < 64) {
        int p = base + t;
        float xi = 0.f, wmv = 0.f; int n = 0;
        if (p < cnt) {
            n = idx[s * CAP + p];
            float xv = x[n];
            float wl = sigmf((xv - mu_min[s]) / sd_min[s]);
            float wh = sigmf((mu_max[s] - xv) / sd_max[s]);
            wmv = wl * wh;
            xi = (xv - centres[s]) / fmaxf(scales[s], 1e-8f);
        }
        xi_s[t] = xi; wm_s[t] = wmv; nn_s[t] = n;
    }
    __syncthreads();

    // layer 0: h[w][p] = tanh(W0[s][w]*xi[p] + b0[s][w])
    #pragma unroll
    for (int k = 0; k < 32; ++k) {
        int flat = k * 256 + t;
        int w = flat >> 6, p = flat & 63;   // w wave-uniform -> scalar W0/b0 loads
        hbuf[0][w * PADH + p] = tanhf(W0[s * WID + w] * xi_s[p] + b0[s * WID + w]);
    }

    int cur = 0;
    int vg = t & 31;    // 32 v-groups of 4 output neurons
    int pg = t >> 5;    // 8 p-groups; each thread does p0 and p0+32
    for (int l = 0; l < NHID; ++l) {
        __syncthreads();   // protect WTs from previous layer's readers + hbuf writes visible
        const float4* src = (const float4*)(WhT + (((s * NHID) + l) << 14));
        float4* dst = (float4*)WTs;
        #pragma unroll
        for (int k = 0; k < 16; ++k) dst[k * 256 + t] = src[k * 256 + t];  // linear, conflict-free
        __syncthreads();

        float a0[4][4] = {{0.f}}, a1[4][4] = {{0.f}};
        const float4* WT4 = (const float4*)WTs;
        const float4* h4  = (const float4*)&hbuf[cur][0];
        #pragma unroll 4
        for (int w = 0; w < WID; ++w) {
            float4 wt = WT4[w * 32 + vg];        // [w][v0..v0+3]
            float4 ha = h4[w * 17 + pg];         // [w][p0..p0+3]
            float4 hb = h4[w * 17 + pg + 8];     // [w][p0+32..p0+35]
            float wtv[4] = {wt.x, wt.y, wt.z, wt.w};
            float hav[4] = {ha.x, ha.y, ha.z, ha.w};
            float hbv[4] = {hb.x, hb.y, hb.z, hb.w};
            #pragma unroll
            for (int i = 0; i < 4; ++i)
                #pragma unroll
                for (int j = 0; j < 4; ++j) {
                    a0[i][j] = fmaf(wtv[i], hav[j], a0[i][j]);
                    a1[i][j] = fmaf(wtv[i], hbv[j], a1[i][j]);
                }
        }
        int v0 = vg * 4, p0 = pg * 4;
        float* ho = &hbuf[1 - cur][0];
        #pragma unroll
        for (int i = 0; i < 4; ++i) {
            float b = bh[((s * NHID) + l) * WID + v0 + i];
            #pragma unroll
            for (int j = 0; j < 4; ++j) {
                ho[(v0 + i) * PADH + p0 + j]      = tanhf(a0[i][j] + b);
                ho[(v0 + i) * PADH + p0 + 32 + j] = tanhf(a1[i][j] + b);
            }
        }
        cur = 1 - cur;
    }
    __syncthreads();

    // output layer + weighted accumulate
    float part = 0.f;
    int p = t & 63, q = t >> 6;             // q wave-uniform -> scalar Wout loads
    const float* hf = &hbuf[cur][0];
    #pragma unroll 8
    for (int w = q * 32; w < q * 32 + 32; ++w)
        part = fmaf(Wout[s * WID + w], hf[w * PADH + p], part);
    red[q][p] = part;
    __syncthreads();
    if (t < 64) {
        float raw = red[0][t] + red[1][t] + red[2][t] + red[3][t] + bout[s];
        if (base + t < cnt) atomicAdd(&out[nn_s[t]], wm_s[t] * raw);
    }
}

extern "C" void kernel_launch(void* const* d_in, const int* in_sizes, int n_in,
                              void* d_out, int out_size, void* d_ws, size_t ws_size,
                              hipStream_t stream) {
    const float* x       = (const float*)d_in[0];
    const float* W0      = (const float*)d_in[1];
    const float* b0      = (const float*)d_in[2];
    const float* Wh      = (const float*)d_in[3];
    const float* bh      = (const float*)d_in[4];
    const float* Wout    = (const float*)d_in[5];
    const float* bout    = (const float*)d_in[6];
    const float* centres = (const float*)d_in[7];
    const float* scales  = (const float*)d_in[8];
    const float* mu_min  = (const float*)d_in[9];
    const float* sd_min  = (const float*)d_in[10];
    const float* mu_max  = (const float*)d_in[11];
    const float* sd_max  = (const float*)d_in[12];
    float* out = (float*)d_out;
    char* ws = (char*)d_ws;
    int*   counts = (int*)ws;
    int*   idx    = (int*)(ws + OFF_IDX);
    float* WhT    = (float*)(ws + OFF_WHT);

    zero_kernel<<<dim3(NPTS / 256), dim3(256), 0, stream>>>(out, counts);
    transpose_kernel<<<dim3(768), dim3(256), 0, stream>>>(Wh, WhT);
    bucket_kernel<<<dim3(NPTS / 256), dim3(256), 0, stream>>>(x, mu_min, sd_min, mu_max, sd_max,
                                                              counts, idx);
    dim3 grid(NS, CAP / 64);   // 16 x 384; blocks beyond count[s] exit immediately
    mlp_kernel<<<grid, dim3(256), 0, stream>>>(x, W0, b0, WhT, bh, Wout, bout,
                                               centres, scales, mu_min, sd_min, mu_max, sd_max,
                                               counts, idx, out);
}

// Round 2
// 192.660 us; speedup vs baseline: 4.7407x; 4.7407x over previous
//
#include <hip/hip_runtime.h>
#include <hip/hip_bf16.h>
#include <math.h>

#define NPTS   65536
#define NS     16
#define WID    128
#define NHID   3
#define CAP    24576
#define ROWB   272              // bytes per point-row in LDS h tile (128 f16 + 16B pad)

// ws layout:
//   [0,64)                    counts[16]
//   [256, 256+16*CAP*4)       idx buckets                  (1.50 MB)
//   [OFF_WF, +1.5MB)          f16 weight fragments WF      (1.50 MB)
#define OFF_IDX 256
#define OFF_WF  (OFF_IDX + NS * CAP * 4)

typedef _Float16 f16x8 __attribute__((ext_vector_type(8)));
typedef _Float16 f16x4 __attribute__((ext_vector_type(4)));
typedef float    f32x4 __attribute__((ext_vector_type(4)));

__device__ __forceinline__ float fast_tanh(float x) {
    // tanh(x) = (E-1)/(E+1), E = 2^(x*2*log2(e)); clamp keeps exp2 in range
    float z = fminf(fmaxf(x * 2.8853900817779268f, -44.f), 44.f);
    float e = __builtin_amdgcn_exp2f(z);
    return __fdividef(e - 1.f, e + 1.f);
}
__device__ __forceinline__ float sigmf(float z) {
    return __fdividef(1.f, 1.f + __builtin_amdgcn_exp2f(fminf(fmaxf(-z * 1.4426950408889634f, -64.f), 64.f)));
}

__global__ void zero_kernel(float* out, int* counts) {
    int i = blockIdx.x * 256 + threadIdx.x;
    if (i < NPTS) out[i] = 0.f;
    if (i < NS) counts[i] = 0;
}

// WF fragment order: frag g = ((sl*8 + vt)*4 + kk)*64 + lane holds
// Wh[sl][v = vt*16 + (lane&15)][w = kk*32 + (lane>>4)*8 .. +7] as 8 f16.
__global__ void prepack_kernel(const float* __restrict__ Wh, _Float16* __restrict__ WF) {
    int g = blockIdx.x * 256 + threadIdx.x;      // 98304 frags
    int sl   = g >> 11;
    int r    = g & 2047;
    int vt   = r >> 8;
    int kk   = (r >> 6) & 3;
    int lane = r & 63;
    int v  = vt * 16 + (lane & 15);
    int w0 = kk * 32 + (lane >> 4) * 8;
    const float* src = Wh + (sl << 14) + v * WID + w0;
    float4 a = *(const float4*)src;
    float4 b = *(const float4*)(src + 4);
    f16x8 o;
    o[0] = (_Float16)a.x; o[1] = (_Float16)a.y; o[2] = (_Float16)a.z; o[3] = (_Float16)a.w;
    o[4] = (_Float16)b.x; o[5] = (_Float16)b.y; o[6] = (_Float16)b.z; o[7] = (_Float16)b.w;
    ((f16x8*)WF)[g] = o;
}

__global__ void bucket_kernel(const float* __restrict__ x,
                              const float* __restrict__ mu_min, const float* __restrict__ sd_min,
                              const float* __restrict__ mu_max, const float* __restrict__ sd_max,
                              int* counts, int* __restrict__ idx) {
    __shared__ int lcnt[NS];
    __shared__ int lbase[NS];
    __shared__ unsigned short litem[NS][256];
    int t = threadIdx.x;
    if (t < NS) lcnt[t] = 0;
    __syncthreads();
    float xv = x[blockIdx.x * 256 + t];
    for (int s = 0; s < NS; ++s) {
        // wm > ~1e-12 iff both logistic args > -27.8 (wm ~ e^min(z1,z2) in the tail)
        float z1 = __fdividef(xv - mu_min[s], sd_min[s]);
        float z2 = __fdividef(mu_max[s] - xv, sd_max[s]);
        if (z1 > -27.8f && z2 > -27.8f) {
            int pos = atomicAdd(&lcnt[s], 1);
            litem[s][pos] = (unsigned short)t;
        }
    }
    __syncthreads();
    if (t < NS) lbase[t] = atomicAdd(&counts[t], lcnt[t]);
    __syncthreads();
    int blockbase = blockIdx.x * 256;
    for (int s = 0; s < NS; ++s) {
        int c = lcnt[s], b = lbase[s];
        for (int j = t; j < c; j += 256) {
            int g = b + j;
            if (g < CAP) idx[s * CAP + g] = blockbase + (int)litem[s][j];
        }
    }
}

__global__ __launch_bounds__(256, 4) void mlp_kernel(
        const float* __restrict__ x,
        const float* __restrict__ W0,   const float* __restrict__ b0,
        const _Float16* __restrict__ WF, const float* __restrict__ bh,
        const float* __restrict__ Wout, const float* __restrict__ bout,
        const float* __restrict__ centres, const float* __restrict__ scales,
        const float* __restrict__ mu_min,  const float* __restrict__ sd_min,
        const float* __restrict__ mu_max,  const float* __restrict__ sd_max,
        const int* __restrict__ counts, const int* __restrict__ idx,
        float* __restrict__ out) {
    __shared__ __align__(16) char hbuf[2][64 * ROWB];   // 2 x 17 KB, layout [p][v] f16, 272B rows
    __shared__ float xi_s[64], wm_s[64];
    __shared__ int   nn_s[64];
    __shared__ float red[4][64];

    int s = blockIdx.x;
    int cnt = counts[s]; if (cnt > CAP) cnt = CAP;
    int base = blockIdx.y * 64;
    if (base >= cnt) return;               // uniform early-out before any barrier
    int t = threadIdx.x;

    if (t < 64) {
        int p = base + t;
        float xi = 0.f, wmv = 0.f; int n = 0;
        if (p < cnt) {
            n = idx[s * CAP + p];
            float xv = x[n];
            float wl = sigmf(__fdividef(xv - mu_min[s], sd_min[s]));
            float wh = sigmf(__fdividef(mu_max[s] - xv, sd_max[s]));
            wmv = wl * wh;
            xi = __fdividef(xv - centres[s], fmaxf(scales[s], 1e-8f));
        }
        xi_s[t] = xi; wm_s[t] = wmv; nn_s[t] = n;
    }
    __syncthreads();

    // ---- layer 0: hbuf[0][p][v] = tanh(W0[v]*xi[p] + b0[v]) ----
    {
        int p  = (t & 15) | ((t >> 6) << 4);
        int cg = (t >> 4) & 3;
        float xi = xi_s[p];
        const float4* W04 = (const float4*)(W0 + s * WID);
        const float4* b04 = (const float4*)(b0 + s * WID);
        char* row = hbuf[0] + p * ROWB;
        #pragma unroll
        for (int k = 0; k < 4; ++k) {
            int v0 = cg * 8 + k * 32;
            float4 wa = W04[v0 / 4],     ba = b04[v0 / 4];
            float4 wb = W04[v0 / 4 + 1], bb = b04[v0 / 4 + 1];
            f16x8 hv;
            hv[0] = (_Float16)fast_tanh(fmaf(wa.x, xi, ba.x));
            hv[1] = (_Float16)fast_tanh(fmaf(wa.y, xi, ba.y));
            hv[2] = (_Float16)fast_tanh(fmaf(wa.z, xi, ba.z));
            hv[3] = (_Float16)fast_tanh(fmaf(wa.w, xi, ba.w));
            hv[4] = (_Float16)fast_tanh(fmaf(wb.x, xi, bb.x));
            hv[5] = (_Float16)fast_tanh(fmaf(wb.y, xi, bb.y));
            hv[6] = (_Float16)fast_tanh(fmaf(wb.z, xi, bb.z));
            hv[7] = (_Float16)fast_tanh(fmaf(wb.w, xi, bb.w));
            *(f16x8*)(row + v0 * 2) = hv;
        }
    }
    __syncthreads();

    // ---- hidden layers via MFMA 16x16x32 f16 ----
    int lane = t & 63, w = t >> 6;         // wave id 0..3
    int lr = lane & 15, lg = lane >> 4;    // frag row/col & k-group
    int cur = 0;
    for (int l = 0; l < NHID; ++l) {
        const f16x8* WFp = (const f16x8*)WF + (size_t)(s * NHID + l) * 2048;
        f32x4 acc[2][4];
        #pragma unroll
        for (int i = 0; i < 2; ++i)
            #pragma unroll
            for (int j = 0; j < 4; ++j) acc[i][j] = (f32x4){0.f, 0.f, 0.f, 0.f};
        const char* hb = hbuf[cur];
        #pragma unroll
        for (int kk = 0; kk < 4; ++kk) {
            f16x8 a0 = WFp[((w * 2 + 0) * 4 + kk) * 64 + lane];
            f16x8 a1 = WFp[((w * 2 + 1) * 4 + kk) * 64 + lane];
            #pragma unroll
            for (int pt = 0; pt < 4; ++pt) {
                f16x8 b = *(const f16x8*)(hb + (pt * 16 + lr) * ROWB + kk * 64 + lg * 16);
                acc[0][pt] = __builtin_amdgcn_mfma_f32_16x16x32_f16(a0, b, acc[0][pt], 0, 0, 0);
                acc[1][pt] = __builtin_amdgcn_mfma_f32_16x16x32_f16(a1, b, acc[1][pt], 0, 0, 0);
            }
        }
        char* ho = hbuf[cur ^ 1];
        #pragma unroll
        for (int i = 0; i < 2; ++i) {
            int v0 = (w * 2 + i) * 16 + lg * 4;
            float4 bias = *(const float4*)(bh + (s * NHID + l) * WID + v0);
            #pragma unroll
            for (int pt = 0; pt < 4; ++pt) {
                f32x4 a = acc[i][pt];
                f16x4 qv;
                qv[0] = (_Float16)fast_tanh(a[0] + bias.x);
                qv[1] = (_Float16)fast_tanh(a[1] + bias.y);
                qv[2] = (_Float16)fast_tanh(a[2] + bias.z);
                qv[3] = (_Float16)fast_tanh(a[3] + bias.w);
                *(f16x4*)(ho + (pt * 16 + lr) * ROWB + v0 * 2) = qv;
            }
        }
        __syncthreads();
        cur ^= 1;
    }

    // ---- output layer: raw[p] = Wout . h[:,p] + bout ----
    {
        int p = t & 63, q = t >> 6;
        const char* hf = hbuf[cur];
        const float* Wo = Wout + s * WID;
        float part = 0.f;
        #pragma unroll
        for (int j = 0; j < 4; ++j) {
            int w0 = q * 32 + j * 8;
            f16x8 hv = *(const f16x8*)(hf + p * ROWB + w0 * 2);
            const float4* w4 = (const float4*)(Wo + w0);
            float4 wa = w4[0], wb = w4[1];
            part += wa.x * (float)hv[0] + wa.y * (float)hv[1] + wa.z * (float)hv[2] + wa.w * (float)hv[3]
                  + wb.x * (float)hv[4] + wb.y * (float)hv[5] + wb.z * (float)hv[6] + wb.w * (float)hv[7];
        }
        red[q][p] = part;
    }
    __syncthreads();
    if (t < 64 && base + t < cnt) {
        float raw = red[0][t] + red[1][t] + red[2][t] + red[3][t] + bout[s];
        atomicAdd(&out[nn_s[t]], wm_s[t] * raw);
    }
}

extern "C" void kernel_launch(void* const* d_in, const int* in_sizes, int n_in,
                              void* d_out, int out_size, void* d_ws, size_t ws_size,
                              hipStream_t stream) {
    const float* x       = (const float*)d_in[0];
    const float* W0      = (const float*)d_in[1];
    const float* b0      = (const float*)d_in[2];
    const float* Wh      = (const float*)d_in[3];
    const float* bh      = (const float*)d_in[4];
    const float* Wout    = (const float*)d_in[5];
    const float* bout    = (const float*)d_in[6];
    const float* centres = (const float*)d_in[7];
    const float* scales  = (const float*)d_in[8];
    const float* mu_min  = (const float*)d_in[9];
    const float* sd_min  = (const float*)d_in[10];
    const float* mu_max  = (const float*)d_in[11];
    const float* sd_max  = (const float*)d_in[12];
    float* out = (float*)d_out;
    char* ws = (char*)d_ws;
    int*      counts = (int*)ws;
    int*      idx    = (int*)(ws + OFF_IDX);
    _Float16* WF     = (_Float16*)(ws + OFF_WF);

    zero_kernel<<<dim3(NPTS / 256), dim3(256), 0, stream>>>(out, counts);
    prepack_kernel<<<dim3(384), dim3(256), 0, stream>>>(Wh, WF);
    bucket_kernel<<<dim3(NPTS / 256), dim3(256), 0, stream>>>(x, mu_min, sd_min, mu_max, sd_max,
                                                              counts, idx);
    dim3 grid(NS, CAP / 64);
    mlp_kernel<<<grid, dim3(256), 0, stream>>>(x, W0, b0, WF, bh, Wout, bout,
                                               centres, scales, mu_min, sd_min, mu_max, sd_max,
                                               counts, idx, out);
}